// Round 2
// baseline (451.510 us; speedup 1.0000x reference)
//
#include <hip/hip_runtime.h>
#include <hip/hip_bf16.h>

// Problem constants (ODST forward):
//   x                        [B=1024, I=256]        f32
//   feature_selection_logits [I=256, N=512, D=6]    f32
//   feature_thresholds       [N=512, D=6]           f32
//   log_temperatures         [N=512, D=6]           f32
//   response                 [N=512, U=16, C=64]    f32
//   out                      [B=1024, U=16]         f32
#define B_SZ 1024
#define I_SZ 256
#define N_SZ 512
#define D_SZ 6
#define U_SZ 16
#define C_SZ 64
#define K_SZ (N_SZ * D_SZ)   // 3072

// ---------------------------------------------------------------------------
// Kernel 1: sparsemax over last axis (D=6) of feature_selection_logits.
// One thread per (i,n) pair. Branchless sorting network.
// ---------------------------------------------------------------------------
__global__ __launch_bounds__(256) void sparsemax_k(
    const float* __restrict__ fsl, float* __restrict__ sel) {
  const int t = blockIdx.x * 256 + threadIdx.x;   // 0 .. I*N-1
  const float* z = fsl + (size_t)t * D_SZ;
  float v[D_SZ], s[D_SZ];
#pragma unroll
  for (int d = 0; d < D_SZ; ++d) { v[d] = z[d]; s[d] = v[d]; }

#define CSWAP(a, b) { float hi = fmaxf(s[a], s[b]); float lo = fminf(s[a], s[b]); s[a] = hi; s[b] = lo; }
#pragma unroll
  for (int r = 0; r < 3; ++r) {
    CSWAP(0, 1) CSWAP(2, 3) CSWAP(4, 5)
    CSWAP(1, 2) CSWAP(3, 4)
  }
#undef CSWAP

  float cs[D_SZ];
  cs[0] = s[0];
#pragma unroll
  for (int j = 1; j < D_SZ; ++j) cs[j] = cs[j - 1] + s[j];
  int kz = 0;
#pragma unroll
  for (int j = 0; j < D_SZ; ++j)
    kz += (1.0f + (float)(j + 1) * s[j] > cs[j]) ? 1 : 0;
  const float tau = (cs[kz - 1] - 1.0f) / (float)kz;

  float* o = sel + (size_t)t * D_SZ;
#pragma unroll
  for (int d = 0; d < D_SZ; ++d) o[d] = fmaxf(v[d] - tau, 0.0f);
}

// ---------------------------------------------------------------------------
// Kernel 2: fv = x @ sel  (M=1024, K=256, N'=3072), fp32 vector GEMM.
// 64x64 tile per block, 4x4 micro-tile per thread, K chunks of 16 via LDS.
// Output stored TRANSPOSED: fvT[k * 1024 + b].
// ---------------------------------------------------------------------------
__global__ __launch_bounds__(256) void gemm_fv(
    const float* __restrict__ x,     // [1024, 256]
    const float* __restrict__ sel,   // [256, 3072]
    float* __restrict__ fvT) {       // [3072, 1024]
  __shared__ float As[16][64];   // [kk][b]
  __shared__ float Bs[16][64];   // [kk][k]

  const int t  = threadIdx.x;
  const int tx = t & 15;
  const int ty = t >> 4;
  const int k0 = blockIdx.x * 64;
  const int b0 = blockIdx.y * 64;

  const int a_row = t >> 2;
  const int a_col = (t & 3) * 4;
  const int b_row = t >> 4;
  const int b_col = (t & 15) * 4;

  float acc[4][4];
#pragma unroll
  for (int i = 0; i < 4; ++i)
#pragma unroll
    for (int j = 0; j < 4; ++j) acc[i][j] = 0.0f;

  for (int kk = 0; kk < I_SZ; kk += 16) {
    const float4 av = *(const float4*)(x + (size_t)(b0 + a_row) * I_SZ + kk + a_col);
    const float4 bv = *(const float4*)(sel + (size_t)(kk + b_row) * K_SZ + k0 + b_col);
    __syncthreads();
    As[a_col + 0][a_row] = av.x;
    As[a_col + 1][a_row] = av.y;
    As[a_col + 2][a_row] = av.z;
    As[a_col + 3][a_row] = av.w;
    *(float4*)&Bs[b_row][b_col] = bv;
    __syncthreads();
#pragma unroll
    for (int kq = 0; kq < 16; ++kq) {
      const float4 a  = *(const float4*)&As[kq][ty * 4];
      const float4 bb = *(const float4*)&Bs[kq][tx * 4];
      const float af[4] = {a.x, a.y, a.z, a.w};
      const float bf[4] = {bb.x, bb.y, bb.z, bb.w};
#pragma unroll
      for (int i = 0; i < 4; ++i)
#pragma unroll
        for (int j = 0; j < 4; ++j) acc[i][j] += af[i] * bf[j];
    }
  }

#pragma unroll
  for (int j = 0; j < 4; ++j) {
    float4 outv = make_float4(acc[0][j], acc[1][j], acc[2][j], acc[3][j]);
    *(float4*)(fvT + (size_t)(k0 + tx * 4 + j) * B_SZ + b0 + ty * 4) = outv;
  }
}

// ---------------------------------------------------------------------------
// Kernel 3: fused bins -> leaf weights -> response dot -> sum over n.
// Grid = 16 b-tiles x 64 n-splits = 1024 blocks (4 blocks/CU, 16 waves/CU —
// R0's 256-block grid capped occupancy at 1 wave/SIMD and left VALU 92% idle).
// Block = 4 waves; lanes = 64 consecutive b (coalesced fvT loads); n is
// wave-uniform so threshold/response reads are scalar broadcasts. Each wave
// handles 2 n values; partial sums accumulated into out via float atomics.
// ---------------------------------------------------------------------------
__global__ __launch_bounds__(256) void tree_k(
    const float* __restrict__ fvT,   // [3072, 1024]
    const float* __restrict__ th,    // [512, 6]
    const float* __restrict__ lt,    // [512, 6]
    const float* __restrict__ resp,  // [512, 16, 64]
    float* __restrict__ out) {       // [1024, 16]
  const int lane   = threadIdx.x & 63;
  const int wave   = threadIdx.x >> 6;   // 0..3
  const int btile  = blockIdx.x & 15;    // 16 b tiles
  const int nsplit = blockIdx.x >> 4;    // 64 n splits
  const int b = btile * 64 + lane;

  float acc[U_SZ];
#pragma unroll
  for (int u = 0; u < U_SZ; ++u) acc[u] = 0.0f;

#pragma unroll 1
  for (int j = 0; j < 2; ++j) {
    const int n = __builtin_amdgcn_readfirstlane(nsplit * 8 + wave * 2 + j);

    float bins0[D_SZ], bins1[D_SZ];
#pragma unroll
    for (int d = 0; d < D_SZ; ++d) {
      const float fv  = fvT[(size_t)(n * D_SZ + d) * B_SZ + b];
      const float tlv = (fv - th[n * D_SZ + d]) * __expf(-lt[n * D_SZ + d]);
      bins1[d] = fminf(fmaxf( 0.5f * tlv + 0.5f, 0.0f), 1.0f);  // +tl bin
      bins0[d] = fminf(fmaxf(-0.5f * tlv + 0.5f, 0.0f), 1.0f);  // -tl bin
    }

    // leaf weights via recursive doubling: w[c] = prod_d (bit_d(c)?bins0:bins1)
    float w[C_SZ];
    w[0] = 1.0f;
#pragma unroll
    for (int d = 0; d < D_SZ; ++d) {
      const int len = 1 << d;
#pragma unroll
      for (int q = len - 1; q >= 0; --q) {
        w[q + len] = w[q] * bins0[d];
        w[q]       = w[q] * bins1[d];
      }
    }

    // out[b, u] += sum_c w[c] * resp[n, u, c]
    const float* r = resp + (size_t)n * (U_SZ * C_SZ);
#pragma unroll
    for (int u = 0; u < U_SZ; ++u) {
      float s = 0.0f;
#pragma unroll
      for (int c = 0; c < C_SZ; ++c) s += w[c] * r[u * C_SZ + c];
      acc[u] += s;
    }
  }

#pragma unroll
  for (int u = 0; u < U_SZ; ++u)
    atomicAdd(&out[(size_t)b * U_SZ + u], acc[u]);
}

// ---------------------------------------------------------------------------
extern "C" void kernel_launch(void* const* d_in, const int* in_sizes, int n_in,
                              void* d_out, int out_size, void* d_ws, size_t ws_size,
                              hipStream_t stream) {
  const float* x    = (const float*)d_in[0];
  const float* fsl  = (const float*)d_in[1];
  const float* th   = (const float*)d_in[2];
  const float* lt   = (const float*)d_in[3];
  const float* resp = (const float*)d_in[4];
  float* out = (float*)d_out;

  float* sel = (float*)d_ws;                       // [256*3072]  (3 MB)
  float* fvT = sel + (size_t)I_SZ * K_SZ;          // [3072*1024] (12 MB)

  // 1) sparsemax: 131072 (i,n) pairs
  sparsemax_k<<<(I_SZ * N_SZ) / 256, 256, 0, stream>>>(fsl, sel);

  // 2) feature-value GEMM (stores transposed)
  dim3 g2(K_SZ / 64, B_SZ / 64);  // 48 x 16
  gemm_fv<<<g2, 256, 0, stream>>>(x, sel, fvT);

  // 3) zero out, then fused tree evaluation with atomic accumulation
  hipMemsetAsync(d_out, 0, (size_t)out_size * sizeof(float), stream);
  tree_k<<<16 * 64, 256, 0, stream>>>(fvT, th, lt, resp, out);
}

// Round 3
// 171.123 us; speedup vs baseline: 2.6385x; 2.6385x over previous
//
#include <hip/hip_runtime.h>
#include <hip/hip_bf16.h>

// Problem constants (ODST forward):
//   x                        [B=1024, I=256]        f32
//   feature_selection_logits [I=256, N=512, D=6]    f32
//   feature_thresholds       [N=512, D=6]           f32
//   log_temperatures         [N=512, D=6]           f32
//   response                 [N=512, U=16, C=64]    f32
//   out                      [B=1024, U=16]         f32
#define B_SZ 1024
#define I_SZ 256
#define N_SZ 512
#define D_SZ 6
#define U_SZ 16
#define C_SZ 64
#define K_SZ (N_SZ * D_SZ)   // 3072
#define NSPLIT 64            // n-parallelism of tree_k (blocks = 16 * NSPLIT)

// ---------------------------------------------------------------------------
// Kernel 1: sparsemax over last axis (D=6). One thread per (i,n) pair.
// ---------------------------------------------------------------------------
__global__ __launch_bounds__(256) void sparsemax_k(
    const float* __restrict__ fsl, float* __restrict__ sel) {
  const int t = blockIdx.x * 256 + threadIdx.x;   // 0 .. I*N-1
  const float* z = fsl + (size_t)t * D_SZ;
  float v[D_SZ], s[D_SZ];
#pragma unroll
  for (int d = 0; d < D_SZ; ++d) { v[d] = z[d]; s[d] = v[d]; }

#define CSWAP(a, b) { float hi = fmaxf(s[a], s[b]); float lo = fminf(s[a], s[b]); s[a] = hi; s[b] = lo; }
#pragma unroll
  for (int r = 0; r < 3; ++r) {
    CSWAP(0, 1) CSWAP(2, 3) CSWAP(4, 5)
    CSWAP(1, 2) CSWAP(3, 4)
  }
#undef CSWAP

  float cs[D_SZ];
  cs[0] = s[0];
#pragma unroll
  for (int j = 1; j < D_SZ; ++j) cs[j] = cs[j - 1] + s[j];
  int kz = 0;
#pragma unroll
  for (int j = 0; j < D_SZ; ++j)
    kz += (1.0f + (float)(j + 1) * s[j] > cs[j]) ? 1 : 0;
  const float tau = (cs[kz - 1] - 1.0f) / (float)kz;

  float* o = sel + (size_t)t * D_SZ;
#pragma unroll
  for (int d = 0; d < D_SZ; ++d) o[d] = fmaxf(v[d] - tau, 0.0f);
}

// ---------------------------------------------------------------------------
// Kernel 2: fv = x @ sel  (M=1024, K=256, N'=3072), fp32 vector GEMM.
// Output stored TRANSPOSED: fvT[k * 1024 + b].
// ---------------------------------------------------------------------------
__global__ __launch_bounds__(256) void gemm_fv(
    const float* __restrict__ x,     // [1024, 256]
    const float* __restrict__ sel,   // [256, 3072]
    float* __restrict__ fvT) {       // [3072, 1024]
  __shared__ float As[16][64];   // [kk][b]
  __shared__ float Bs[16][64];   // [kk][k]

  const int t  = threadIdx.x;
  const int tx = t & 15;
  const int ty = t >> 4;
  const int k0 = blockIdx.x * 64;
  const int b0 = blockIdx.y * 64;

  const int a_row = t >> 2;
  const int a_col = (t & 3) * 4;
  const int b_row = t >> 4;
  const int b_col = (t & 15) * 4;

  float acc[4][4];
#pragma unroll
  for (int i = 0; i < 4; ++i)
#pragma unroll
    for (int j = 0; j < 4; ++j) acc[i][j] = 0.0f;

  for (int kk = 0; kk < I_SZ; kk += 16) {
    const float4 av = *(const float4*)(x + (size_t)(b0 + a_row) * I_SZ + kk + a_col);
    const float4 bv = *(const float4*)(sel + (size_t)(kk + b_row) * K_SZ + k0 + b_col);
    __syncthreads();
    As[a_col + 0][a_row] = av.x;
    As[a_col + 1][a_row] = av.y;
    As[a_col + 2][a_row] = av.z;
    As[a_col + 3][a_row] = av.w;
    *(float4*)&Bs[b_row][b_col] = bv;
    __syncthreads();
#pragma unroll
    for (int kq = 0; kq < 16; ++kq) {
      const float4 a  = *(const float4*)&As[kq][ty * 4];
      const float4 bb = *(const float4*)&Bs[kq][tx * 4];
      const float af[4] = {a.x, a.y, a.z, a.w};
      const float bf[4] = {bb.x, bb.y, bb.z, bb.w};
#pragma unroll
      for (int i = 0; i < 4; ++i)
#pragma unroll
        for (int j = 0; j < 4; ++j) acc[i][j] += af[i] * bf[j];
    }
  }

#pragma unroll
  for (int j = 0; j < 4; ++j) {
    float4 outv = make_float4(acc[0][j], acc[1][j], acc[2][j], acc[3][j]);
    *(float4*)(fvT + (size_t)(k0 + tx * 4 + j) * B_SZ + b0 + ty * 4) = outv;
  }
}

// ---------------------------------------------------------------------------
// Kernel 3: fused bins -> leaf weights -> response dot. NO ATOMICS (R1's
// 1M wave-atomics touched 64 distinct lines each -> 131 MB of L2 writeback
// and total serialization). Each block LDS-reduces its 4 waves and writes one
// coalesced [64 b x 16 u] fp32 partial tile; reduce_k sums over n-splits.
// Grid = 16 b-tiles x 64 n-splits = 1024 blocks (4/CU, 16 waves/CU).
// ---------------------------------------------------------------------------
__global__ __launch_bounds__(256) void tree_k(
    const float* __restrict__ fvT,   // [3072, 1024]
    const float* __restrict__ th,    // [512, 6]
    const float* __restrict__ lt,    // [512, 6]
    const float* __restrict__ resp,  // [512, 16, 64]
    float* __restrict__ part) {      // [1024 blocks][64*16]
  __shared__ float red[4][64][17];   // +1 pad: stride 17 -> 2-way bank alias (free)
  const int lane   = threadIdx.x & 63;
  const int wave   = threadIdx.x >> 6;   // 0..3
  const int btile  = blockIdx.x & 15;    // 16 b tiles
  const int nsplit = blockIdx.x >> 4;    // 64 n splits
  const int b = btile * 64 + lane;

  float acc[U_SZ];
#pragma unroll
  for (int u = 0; u < U_SZ; ++u) acc[u] = 0.0f;

#pragma unroll 1
  for (int j = 0; j < 2; ++j) {
    const int n = __builtin_amdgcn_readfirstlane(nsplit * 8 + wave * 2 + j);

    float bins0[D_SZ], bins1[D_SZ];
#pragma unroll
    for (int d = 0; d < D_SZ; ++d) {
      const float fv  = fvT[(size_t)(n * D_SZ + d) * B_SZ + b];
      const float tlv = (fv - th[n * D_SZ + d]) * __expf(-lt[n * D_SZ + d]);
      bins1[d] = fminf(fmaxf( 0.5f * tlv + 0.5f, 0.0f), 1.0f);  // +tl bin
      bins0[d] = fminf(fmaxf(-0.5f * tlv + 0.5f, 0.0f), 1.0f);  // -tl bin
    }

    // leaf weights via recursive doubling
    float w[C_SZ];
    w[0] = 1.0f;
#pragma unroll
    for (int d = 0; d < D_SZ; ++d) {
      const int len = 1 << d;
#pragma unroll
      for (int q = len - 1; q >= 0; --q) {
        w[q + len] = w[q] * bins0[d];
        w[q]       = w[q] * bins1[d];
      }
    }

    // acc[u] += sum_c w[c] * resp[n, u, c]   (resp reads are scalar/broadcast)
    const float* r = resp + (size_t)n * (U_SZ * C_SZ);
#pragma unroll
    for (int u = 0; u < U_SZ; ++u) {
      float s = 0.0f;
#pragma unroll
      for (int c = 0; c < C_SZ; ++c) s += w[c] * r[u * C_SZ + c];
      acc[u] += s;
    }
  }

  // cross-wave reduction in LDS, then one coalesced partial tile per block
#pragma unroll
  for (int u = 0; u < U_SZ; ++u) red[wave][lane][u] = acc[u];
  __syncthreads();

  const int t = threadIdx.x;
  float4 o;
  float* op = (float*)&o;
#pragma unroll
  for (int j = 0; j < 4; ++j) {
    const int e  = t * 4 + j;        // 0..1023 = bl*16 + u
    const int bl = e >> 4;
    const int u  = e & 15;
    op[j] = red[0][bl][u] + red[1][bl][u] + red[2][bl][u] + red[3][bl][u];
  }
  *(float4*)(part + (size_t)blockIdx.x * 1024 + t * 4) = o;
}

// ---------------------------------------------------------------------------
// Kernel 4: out[b][u] = sum over 64 n-splits of part tiles. Writes out
// directly (no memset needed).
// ---------------------------------------------------------------------------
__global__ __launch_bounds__(256) void reduce_k(
    const float* __restrict__ part, float* __restrict__ out) {
  const int g = blockIdx.x * 256 + threadIdx.x;  // 0..16383 = btile*1024 + bl*16 + u
  const int btile = g >> 10;
  const int inner = g & 1023;
  float s = 0.0f;
#pragma unroll
  for (int ns = 0; ns < NSPLIT; ++ns)
    s += part[(size_t)(ns * 16 + btile) * 1024 + inner];
  out[g] = s;
}

// ---------------------------------------------------------------------------
extern "C" void kernel_launch(void* const* d_in, const int* in_sizes, int n_in,
                              void* d_out, int out_size, void* d_ws, size_t ws_size,
                              hipStream_t stream) {
  const float* x    = (const float*)d_in[0];
  const float* fsl  = (const float*)d_in[1];
  const float* th   = (const float*)d_in[2];
  const float* lt   = (const float*)d_in[3];
  const float* resp = (const float*)d_in[4];
  float* out = (float*)d_out;

  float* sel  = (float*)d_ws;                      // [256*3072]   (3 MB)
  float* fvT  = sel + (size_t)I_SZ * K_SZ;         // [3072*1024]  (12 MB)
  float* part = fvT + (size_t)K_SZ * B_SZ;         // [1024*1024]  (4 MB)

  // 1) sparsemax: 131072 (i,n) pairs
  sparsemax_k<<<(I_SZ * N_SZ) / 256, 256, 0, stream>>>(fsl, sel);

  // 2) feature-value GEMM (stores transposed)
  dim3 g2(K_SZ / 64, B_SZ / 64);  // 48 x 16
  gemm_fv<<<g2, 256, 0, stream>>>(x, sel, fvT);

  // 3) tree evaluation -> per-block partials (no atomics)
  tree_k<<<16 * NSPLIT, 256, 0, stream>>>(fvT, th, lt, resp, part);

  // 4) reduce partials -> out
  reduce_k<<<(B_SZ * U_SZ) / 256, 256, 0, stream>>>(part, out);
}

// Round 4
// 115.177 us; speedup vs baseline: 3.9201x; 1.4857x over previous
//
#include <hip/hip_runtime.h>
#include <hip/hip_bf16.h>

// Problem constants (ODST forward):
//   x                        [B=1024, I=256]        f32
//   feature_selection_logits [I=256, N=512, D=6]    f32
//   feature_thresholds       [N=512, D=6]           f32
//   log_temperatures         [N=512, D=6]           f32
//   response                 [N=512, U=16, C=64]    f32
//   out                      [B=1024, U=16]         f32
#define B_SZ 1024
#define I_SZ 256
#define N_SZ 512
#define D_SZ 6
#define U_SZ 16
#define C_SZ 64
#define K_SZ (N_SZ * D_SZ)   // 3072
#define NSPLIT 64            // tree n-splits: 1024 blocks, 8 n per block

typedef __bf16 bf16_t;
typedef bf16_t bf16x8 __attribute__((ext_vector_type(8)));
typedef bf16_t bf16x4 __attribute__((ext_vector_type(4)));
typedef float  f32x4  __attribute__((ext_vector_type(4)));

// ---------------------------------------------------------------------------
// Kernel 0: dtype prep. x -> bf16, resp -> bf16, elt = exp(-lt).
// grid = 256 (x) + 512 (resp) + 12 (elt) blocks of 256 threads.
// ---------------------------------------------------------------------------
__global__ __launch_bounds__(256) void cvt_k(
    const float* __restrict__ x, const float* __restrict__ resp,
    const float* __restrict__ lt,
    bf16_t* __restrict__ xb, bf16_t* __restrict__ respb,
    float* __restrict__ elt) {
  const int bid = blockIdx.x;
  if (bid < 256) {
    const int idx = (bid * 256 + threadIdx.x) * 4;     // < 262144
    const float4 v = *(const float4*)(x + idx);
    bf16x4 o; o[0] = (bf16_t)v.x; o[1] = (bf16_t)v.y; o[2] = (bf16_t)v.z; o[3] = (bf16_t)v.w;
    *(bf16x4*)(xb + idx) = o;
  } else if (bid < 768) {
    const int idx = ((bid - 256) * 256 + threadIdx.x) * 4;  // < 524288
    const float4 v = *(const float4*)(resp + idx);
    bf16x4 o; o[0] = (bf16_t)v.x; o[1] = (bf16_t)v.y; o[2] = (bf16_t)v.z; o[3] = (bf16_t)v.w;
    *(bf16x4*)(respb + idx) = o;
  } else {
    const int i = (bid - 768) * 256 + threadIdx.x;     // < 3072
    elt[i] = __expf(-lt[i]);
  }
}

// ---------------------------------------------------------------------------
// Kernel 1: sparsemax over D=6 + transpose to selT[k'=n*6+d][i] in bf16
// (A-operand layout for the MFMA feature GEMM). Block handles 16 i x 16 n;
// grid = (N/16=32, I/16=16). Phase 1: coalesced read + sparsemax -> LDS
// tile; phase 2: 192 threads emit 16-B bf16x8 rows of selT.
// ---------------------------------------------------------------------------
__global__ __launch_bounds__(256) void sparsemax_k(
    const float* __restrict__ fsl, bf16_t* __restrict__ selT) {
  __shared__ float sT[96][17];    // [n_loc*6+d][i_loc], +1 pad
  const int t = threadIdx.x;
  const int i_loc = t >> 4, n_loc = t & 15;
  const int n0 = blockIdx.x * 16, i0 = blockIdx.y * 16;

  const float* z = fsl + ((size_t)(i0 + i_loc) * N_SZ + (n0 + n_loc)) * D_SZ;
  float v[D_SZ], s[D_SZ];
#pragma unroll
  for (int d = 0; d < D_SZ; ++d) { v[d] = z[d]; s[d] = v[d]; }

#define CSWAP(a, b) { float hi = fmaxf(s[a], s[b]); float lo = fminf(s[a], s[b]); s[a] = hi; s[b] = lo; }
#pragma unroll
  for (int r = 0; r < 3; ++r) {
    CSWAP(0, 1) CSWAP(2, 3) CSWAP(4, 5)
    CSWAP(1, 2) CSWAP(3, 4)
  }
#undef CSWAP

  float cs[D_SZ];
  cs[0] = s[0];
#pragma unroll
  for (int j = 1; j < D_SZ; ++j) cs[j] = cs[j - 1] + s[j];
  int kz = 0;
#pragma unroll
  for (int j = 0; j < D_SZ; ++j)
    kz += (1.0f + (float)(j + 1) * s[j] > cs[j]) ? 1 : 0;
  const float tau = (cs[kz - 1] - 1.0f) / (float)kz;

#pragma unroll
  for (int d = 0; d < D_SZ; ++d)
    sT[n_loc * 6 + d][i_loc] = fmaxf(v[d] - tau, 0.0f);
  __syncthreads();

  if (t < 192) {
    const int row = t >> 1, half = t & 1;   // row: 96 local k' rows
    bf16x8 o;
#pragma unroll
    for (int jj = 0; jj < 8; ++jj) o[jj] = (bf16_t)sT[row][half * 8 + jj];
    *(bf16x8*)(selT + (size_t)(n0 * 6 + row) * I_SZ + i0 + half * 8) = o;
  }
}

// ---------------------------------------------------------------------------
// Kernel 2: fvT[k'][b] = sum_i selT[k'][i] * x[b][i] via mfma_16x16x32_bf16.
// A-frag: lane holds selT[m0+(l&15)][kk + (l>>4)*8 + j] (8 consecutive i).
// B-frag: lane holds x[b0+s*16+(l&15)][kk + (l>>4)*8 + j] (8 consecutive i).
// Block = 4 waves: 64 k' x 64 b; grid = (48, 16) = 768 blocks.
// ---------------------------------------------------------------------------
__global__ __launch_bounds__(256) void gemm_mfma(
    const bf16_t* __restrict__ selT,  // [3072][256]
    const bf16_t* __restrict__ xb,    // [1024][256]
    float* __restrict__ fvT) {        // [3072][1024]
  const int lane = threadIdx.x & 63, wave = threadIdx.x >> 6;
  const int lm = lane & 15, q = lane >> 4;
  const int m0 = blockIdx.x * 64 + wave * 16;   // k' row tile (per wave)
  const int b0 = blockIdx.y * 64;               // b col tile (4 sub-tiles)

  f32x4 acc[4];
#pragma unroll
  for (int s = 0; s < 4; ++s) acc[s] = (f32x4){0.f, 0.f, 0.f, 0.f};

  const bf16_t* arow = selT + (size_t)(m0 + lm) * I_SZ + q * 8;
#pragma unroll
  for (int kk = 0; kk < I_SZ; kk += 32) {
    const bf16x8 a = *(const bf16x8*)(arow + kk);
#pragma unroll
    for (int s = 0; s < 4; ++s) {
      const bf16x8 bv = *(const bf16x8*)(xb + (size_t)(b0 + s * 16 + lm) * I_SZ + kk + q * 8);
      acc[s] = __builtin_amdgcn_mfma_f32_16x16x32_bf16(a, bv, acc[s], 0, 0, 0);
    }
  }

  // C/D: col(=b) = lane&15, row(=k') = (lane>>4)*4 + r
#pragma unroll
  for (int s = 0; s < 4; ++s)
#pragma unroll
    for (int r = 0; r < 4; ++r)
      fvT[(size_t)(m0 + q * 4 + r) * B_SZ + b0 + s * 16 + lm] = acc[s][r];
}

// ---------------------------------------------------------------------------
// Kernel 3: tree eval via MFMA. out-tile [16 b x 16 u] per wave, K = n*64+c.
// c-bit split: jj=bits0-2 (A-frag element), q=bits3-4 (lane quad), chunk=bit5
// (two mfma per n). Lane computes w(c) = prefix8[jj] * fq(q) * g(chunk) for
// exactly its own A-fragment -> no LDS, no shuffles. B-frag = 16 B of
// resp_bf16[n][u=l&15][c] directly from global. Grid = 16 btiles x 64 ns.
// ---------------------------------------------------------------------------
__global__ __launch_bounds__(256) void tree_mfma(
    const float* __restrict__ fvT,    // [3072][1024]
    const float* __restrict__ th,     // [512][6]
    const float* __restrict__ elt,    // [512][6] = exp(-lt)
    const bf16_t* __restrict__ respb, // [512][16][64]
    float* __restrict__ part) {       // [64 ns][1024 b][16 u]
  const int lane = threadIdx.x & 63, wave = threadIdx.x >> 6;
  const int lm = lane & 15, q = lane >> 4;
  const int btile = blockIdx.x & 15, ns = blockIdx.x >> 4;
  const int b = btile * 64 + wave * 16 + lm;

  f32x4 acc = (f32x4){0.f, 0.f, 0.f, 0.f};

#pragma unroll
  for (int j = 0; j < 8; ++j) {
    const int n = ns * 8 + j;
    float b0v[D_SZ], b1v[D_SZ];
#pragma unroll
    for (int d = 0; d < D_SZ; ++d) {
      const float fv = fvT[(size_t)(n * 6 + d) * B_SZ + b];
      const float tl = (fv - th[n * 6 + d]) * elt[n * 6 + d];
      b1v[d] = fminf(fmaxf(0.5f * tl + 0.5f, 0.0f), 1.0f);  // stack idx 1 (bit=0)
      b0v[d] = fminf(fmaxf(0.5f - 0.5f * tl, 0.0f), 1.0f);  // stack idx 0 (bit=1)
    }
    // prefix over bits 0..2 (factor: bit set -> b0v, clear -> b1v)
    float p2[2], p4[4], p8[8];
    p2[0] = b1v[0]; p2[1] = b0v[0];
#pragma unroll
    for (int i = 0; i < 4; ++i) p4[i] = p2[i & 1] * ((i & 2) ? b0v[1] : b1v[1]);
#pragma unroll
    for (int i = 0; i < 8; ++i) p8[i] = p4[i & 3] * ((i & 4) ? b0v[2] : b1v[2]);
    const float f3 = (q & 1) ? b0v[3] : b1v[3];
    const float f4 = (q & 2) ? b0v[4] : b1v[4];
    const float fq = f3 * f4;
    const float g0 = fq * b1v[5];   // chunk 0: bit5 = 0
    const float g1 = fq * b0v[5];   // chunk 1: bit5 = 1

    bf16x8 a0, a1;
#pragma unroll
    for (int jj = 0; jj < 8; ++jj) {
      a0[jj] = (bf16_t)(p8[jj] * g0);
      a1[jj] = (bf16_t)(p8[jj] * g1);
    }
    const bf16_t* rb = respb + (size_t)n * (U_SZ * C_SZ) + lm * C_SZ + q * 8;
    const bf16x8 bv0 = *(const bf16x8*)(rb);
    const bf16x8 bv1 = *(const bf16x8*)(rb + 32);
    acc = __builtin_amdgcn_mfma_f32_16x16x32_bf16(a0, bv0, acc, 0, 0, 0);
    acc = __builtin_amdgcn_mfma_f32_16x16x32_bf16(a1, bv1, acc, 0, 0, 0);
  }

  // C/D: col(=u) = lane&15, row(=b within 16) = (lane>>4)*4 + r
#pragma unroll
  for (int r = 0; r < 4; ++r)
    part[(size_t)ns * (B_SZ * U_SZ) +
         (size_t)(btile * 64 + wave * 16 + q * 4 + r) * U_SZ + lm] = acc[r];
}

// ---------------------------------------------------------------------------
// Kernel 4: out[b][u] = sum over 64 n-splits.
// ---------------------------------------------------------------------------
__global__ __launch_bounds__(256) void reduce_k(
    const float* __restrict__ part, float* __restrict__ out) {
  const int g = blockIdx.x * 256 + threadIdx.x;   // 0..16383
  float s = 0.0f;
#pragma unroll
  for (int ns = 0; ns < NSPLIT; ++ns)
    s += part[(size_t)ns * (B_SZ * U_SZ) + g];
  out[g] = s;
}

// ---------------------------------------------------------------------------
extern "C" void kernel_launch(void* const* d_in, const int* in_sizes, int n_in,
                              void* d_out, int out_size, void* d_ws, size_t ws_size,
                              hipStream_t stream) {
  const float* x    = (const float*)d_in[0];
  const float* fsl  = (const float*)d_in[1];
  const float* th   = (const float*)d_in[2];
  const float* lt   = (const float*)d_in[3];
  const float* resp = (const float*)d_in[4];
  float* out = (float*)d_out;

  // workspace layout (18.3 MB total; selT aliases part — selT dead after gemm)
  char* w = (char*)d_ws;
  float*  fvT   = (float*)(w);                         // 12582912 B
  bf16_t* xb    = (bf16_t*)(w + 12582912);             //   524288 B
  bf16_t* respb = (bf16_t*)(w + 13107200);             //  1048576 B
  float*  elt   = (float*)(w + 14155776);              //    12288 B
  char*   scratch = w + 14168064;                      // max(selT 1.5MB, part 4MB)
  bf16_t* selT  = (bf16_t*)scratch;                    // [3072][256] bf16
  float*  part  = (float*)scratch;                     // [64][16384] f32

  // 0) bf16 conversions + exp(-lt)
  cvt_k<<<780, 256, 0, stream>>>(x, resp, lt, xb, respb, elt);

  // 1) sparsemax -> selT (bf16, transposed)
  dim3 g1(N_SZ / 16, I_SZ / 16);   // 32 x 16
  sparsemax_k<<<g1, 256, 0, stream>>>(fsl, selT);

  // 2) feature GEMM (MFMA) -> fvT
  dim3 g2(K_SZ / 64, B_SZ / 64);   // 48 x 16
  gemm_mfma<<<g2, 256, 0, stream>>>(selT, xb, fvT);

  // 3) tree eval (MFMA) -> partials   (overwrites selT region; selT is dead)
  tree_mfma<<<16 * NSPLIT, 256, 0, stream>>>(fvT, th, elt, respb, part);

  // 4) reduce partials -> out
  reduce_k<<<(B_SZ * U_SZ) / 256, 256, 0, stream>>>(part, out);
}

// Round 5
// 93.480 us; speedup vs baseline: 4.8300x; 1.2321x over previous
//
#include <hip/hip_runtime.h>
#include <hip/hip_bf16.h>

// Problem constants (ODST forward):
//   x    [B=1024, I=256]  fsl [I=256,N=512,D=6]  th/lt [N=512,D=6]
//   resp [N=512, U=16, C=64]   out [B=1024, U=16]
#define B_SZ 1024
#define I_SZ 256
#define N_SZ 512
#define D_SZ 6
#define U_SZ 16
#define C_SZ 64
#define K_SZ (N_SZ * D_SZ)   // 3072
#define NSPLIT 64            // 8 n (48 k' rows) per fused block

typedef __bf16 bf16_t;
typedef bf16_t bf16x8 __attribute__((ext_vector_type(8)));
typedef bf16_t bf16x4 __attribute__((ext_vector_type(4)));
typedef float  f32x4  __attribute__((ext_vector_type(4)));

// ---------------------------------------------------------------------------
// Kernel 0 (prep): bf16 casts of x/resp, elt=exp(-lt), sparsemax->selT bf16.
// One launch, branch on blockIdx (all branches wave-uniform).
//   bid [0,256)    : x -> xb
//   bid [256,768)  : resp -> respb
//   bid [768,780)  : elt = exp(-lt)
//   bid [780,1292) : sparsemax + transpose -> selT[k'=n*6+d][i]
// ---------------------------------------------------------------------------
__global__ __launch_bounds__(256) void prep_k(
    const float* __restrict__ x, const float* __restrict__ resp,
    const float* __restrict__ lt, const float* __restrict__ fsl,
    bf16_t* __restrict__ xb, bf16_t* __restrict__ respb,
    float* __restrict__ elt, bf16_t* __restrict__ selT) {
  __shared__ float sT[96][17];
  const int bid = blockIdx.x;
  if (bid < 256) {
    const int idx = (bid * 256 + threadIdx.x) * 4;
    const float4 v = *(const float4*)(x + idx);
    bf16x4 o; o[0] = (bf16_t)v.x; o[1] = (bf16_t)v.y; o[2] = (bf16_t)v.z; o[3] = (bf16_t)v.w;
    *(bf16x4*)(xb + idx) = o;
  } else if (bid < 768) {
    const int idx = ((bid - 256) * 256 + threadIdx.x) * 4;
    const float4 v = *(const float4*)(resp + idx);
    bf16x4 o; o[0] = (bf16_t)v.x; o[1] = (bf16_t)v.y; o[2] = (bf16_t)v.z; o[3] = (bf16_t)v.w;
    *(bf16x4*)(respb + idx) = o;
  } else if (bid < 780) {
    const int i = (bid - 768) * 256 + threadIdx.x;
    elt[i] = __expf(-lt[i]);
  } else {
    const int sbid = bid - 780;                    // 0..511
    const int t = threadIdx.x;
    const int i_loc = t >> 4, n_loc = t & 15;
    const int n0 = (sbid & 31) * 16, i0 = (sbid >> 5) * 16;

    const float* z = fsl + ((size_t)(i0 + i_loc) * N_SZ + (n0 + n_loc)) * D_SZ;
    float v[D_SZ], s[D_SZ];
#pragma unroll
    for (int d = 0; d < D_SZ; ++d) { v[d] = z[d]; s[d] = v[d]; }

#define CSWAP(a, b) { float hi = fmaxf(s[a], s[b]); float lo = fminf(s[a], s[b]); s[a] = hi; s[b] = lo; }
#pragma unroll
    for (int r = 0; r < 3; ++r) {
      CSWAP(0, 1) CSWAP(2, 3) CSWAP(4, 5)
      CSWAP(1, 2) CSWAP(3, 4)
    }
#undef CSWAP

    float cs[D_SZ];
    cs[0] = s[0];
#pragma unroll
    for (int j = 1; j < D_SZ; ++j) cs[j] = cs[j - 1] + s[j];
    int kz = 0;
#pragma unroll
    for (int j = 0; j < D_SZ; ++j)
      kz += (1.0f + (float)(j + 1) * s[j] > cs[j]) ? 1 : 0;
    const float tau = (cs[kz - 1] - 1.0f) / (float)kz;

#pragma unroll
    for (int d = 0; d < D_SZ; ++d)
      sT[n_loc * 6 + d][i_loc] = fmaxf(v[d] - tau, 0.0f);
    __syncthreads();

    if (t < 192) {
      const int row = t >> 1, half = t & 1;
      bf16x8 o;
#pragma unroll
      for (int jj = 0; jj < 8; ++jj) o[jj] = (bf16_t)sT[row][half * 8 + jj];
      *(bf16x8*)(selT + (size_t)(n0 * 6 + row) * I_SZ + i0 + half * 8) = o;
    }
  }
}

// ---------------------------------------------------------------------------
// Kernel 1 (fused): feature-GEMM (MFMA) -> LDS fv tile -> tree eval (MFMA).
// Block (btile, ns) owns b in [btile*64, +64) and n in [ns*8, +8) = 48 k'.
// Phase A: waves 0-2 each compute a 16k' x 64b MFMA tile (A=selT rows,
//   B=xb rows, both direct-from-global 16B frags) and store f32 to LDS
//   fv[48][68] (no HBM round-trip — R3 wrote/re-read 24 MB of fvT).
// Phase B: all 4 waves: wave handles 16 b; per n computes bins (LDS fv
//   broadcast reads), per-lane leaf-weight A-frags (c-bits: jj=0-2 in frag,
//   q=3-4 lane quad, chunk=5), 2 MFMA vs respb -> [16b x 16u] partial.
// ---------------------------------------------------------------------------
__global__ __launch_bounds__(256) void fused_k(
    const bf16_t* __restrict__ selT,  // [3072][256]
    const bf16_t* __restrict__ xb,    // [1024][256]
    const float* __restrict__ th,     // [512][6]
    const float* __restrict__ elt,    // [512][6]
    const bf16_t* __restrict__ respb, // [512][16][64]
    float* __restrict__ part) {       // [64 ns][1024 b][16 u]
  __shared__ float fv[48][68];        // [k'_loc][b_loc], pad 68
  const int lane = threadIdx.x & 63, wave = threadIdx.x >> 6;
  const int lm = lane & 15, q = lane >> 4;
  const int btile = blockIdx.x & 15, ns = blockIdx.x >> 4;

  // ---- Phase A: GEMM 48 k' x 64 b (waves 0-2)
  if (wave < 3) {
    f32x4 acc[4];
#pragma unroll
    for (int s = 0; s < 4; ++s) acc[s] = (f32x4){0.f, 0.f, 0.f, 0.f};
    const bf16_t* arow = selT + (size_t)(ns * 48 + wave * 16 + lm) * I_SZ + q * 8;
    const bf16_t* brow = xb + (size_t)(btile * 64 + lm) * I_SZ + q * 8;
#pragma unroll
    for (int kk = 0; kk < I_SZ; kk += 32) {
      const bf16x8 a = *(const bf16x8*)(arow + kk);
#pragma unroll
      for (int s = 0; s < 4; ++s) {
        const bf16x8 bv = *(const bf16x8*)(brow + (size_t)s * 16 * I_SZ + kk);
        acc[s] = __builtin_amdgcn_mfma_f32_16x16x32_bf16(a, bv, acc[s], 0, 0, 0);
      }
    }
    // C/D: row(k'_loc within 16) = q*4+r, col(b_loc within 16) = lm
#pragma unroll
    for (int s = 0; s < 4; ++s)
#pragma unroll
      for (int r = 0; r < 4; ++r)
        fv[wave * 16 + q * 4 + r][s * 16 + lm] = acc[s][r];
  }
  __syncthreads();

  // ---- Phase B: tree eval, wave handles b_loc in [wave*16, +16)
  f32x4 acc = (f32x4){0.f, 0.f, 0.f, 0.f};
  const int bloc = wave * 16 + lm;

#pragma unroll
  for (int j = 0; j < 8; ++j) {
    const int n = ns * 8 + j;
    float b0v[D_SZ], b1v[D_SZ];
#pragma unroll
    for (int d = 0; d < D_SZ; ++d) {
      const float fvv = fv[j * 6 + d][bloc];
      const float tl  = (fvv - th[n * 6 + d]) * elt[n * 6 + d];
      b1v[d] = fminf(fmaxf(0.5f * tl + 0.5f, 0.0f), 1.0f);  // bit = 0
      b0v[d] = fminf(fmaxf(0.5f - 0.5f * tl, 0.0f), 1.0f);  // bit = 1
    }
    float p2[2], p4[4], p8[8];
    p2[0] = b1v[0]; p2[1] = b0v[0];
#pragma unroll
    for (int i = 0; i < 4; ++i) p4[i] = p2[i & 1] * ((i & 2) ? b0v[1] : b1v[1]);
#pragma unroll
    for (int i = 0; i < 8; ++i) p8[i] = p4[i & 3] * ((i & 4) ? b0v[2] : b1v[2]);
    const float f3 = (q & 1) ? b0v[3] : b1v[3];
    const float f4 = (q & 2) ? b0v[4] : b1v[4];
    const float fq = f3 * f4;
    const float g0 = fq * b1v[5];   // chunk 0: bit5 = 0
    const float g1 = fq * b0v[5];   // chunk 1: bit5 = 1

    bf16x8 a0, a1;
#pragma unroll
    for (int jj = 0; jj < 8; ++jj) {
      a0[jj] = (bf16_t)(p8[jj] * g0);
      a1[jj] = (bf16_t)(p8[jj] * g1);
    }
    const bf16_t* rb = respb + (size_t)n * (U_SZ * C_SZ) + lm * C_SZ + q * 8;
    const bf16x8 bv0 = *(const bf16x8*)(rb);
    const bf16x8 bv1 = *(const bf16x8*)(rb + 32);
    acc = __builtin_amdgcn_mfma_f32_16x16x32_bf16(a0, bv0, acc, 0, 0, 0);
    acc = __builtin_amdgcn_mfma_f32_16x16x32_bf16(a1, bv1, acc, 0, 0, 0);
  }

  // C/D: col(u) = lm, row(b within 16) = q*4 + r
#pragma unroll
  for (int r = 0; r < 4; ++r)
    part[(size_t)ns * (B_SZ * U_SZ) +
         (size_t)(btile * 64 + wave * 16 + q * 4 + r) * U_SZ + lm] = acc[r];
}

// ---------------------------------------------------------------------------
// Kernel 2: out = sum over 64 n-splits. 256 blocks (R3's 64-block version
// was 0.25 blocks/CU — pure latency). Block = 64 outputs x 4 ns-groups of 16.
// ---------------------------------------------------------------------------
__global__ __launch_bounds__(256) void reduce_k(
    const float* __restrict__ part, float* __restrict__ out) {
  __shared__ float red[4][64];
  const int t = threadIdx.x;
  const int o = blockIdx.x * 64 + (t & 63);
  const int g = t >> 6;
  float s = 0.0f;
#pragma unroll
  for (int k = 0; k < 16; ++k)
    s += part[(size_t)(g * 16 + k) * (B_SZ * U_SZ) + o];
  red[g][t & 63] = s;
  __syncthreads();
  if (t < 64)
    out[blockIdx.x * 64 + t] = red[0][t] + red[1][t] + red[2][t] + red[3][t];
}

// ---------------------------------------------------------------------------
extern "C" void kernel_launch(void* const* d_in, const int* in_sizes, int n_in,
                              void* d_out, int out_size, void* d_ws, size_t ws_size,
                              hipStream_t stream) {
  const float* x    = (const float*)d_in[0];
  const float* fsl  = (const float*)d_in[1];
  const float* th   = (const float*)d_in[2];
  const float* lt   = (const float*)d_in[3];
  const float* resp = (const float*)d_in[4];
  float* out = (float*)d_out;

  // workspace (~7.4 MB total; fvT eliminated by fusion)
  char* w = (char*)d_ws;
  bf16_t* xb    = (bf16_t*)(w);                 //  524288 B
  bf16_t* respb = (bf16_t*)(w + 524288);        // 1048576 B
  float*  elt   = (float*)(w + 1572864);        //   12288 B
  bf16_t* selT  = (bf16_t*)(w + 1585152);       // 1572864 B  [3072][256]
  float*  part  = (float*)(w + 3158016);        // 4194304 B  [64][16384]

  // 0) prep: casts + exp(-lt) + sparsemax/transpose
  prep_k<<<1292, 256, 0, stream>>>(x, resp, lt, fsl, xb, respb, elt, selT);

  // 1) fused GEMM + tree eval -> partials
  fused_k<<<16 * NSPLIT, 256, 0, stream>>>(selT, xb, th, elt, respb, part);

  // 2) reduce partials -> out
  reduce_k<<<(B_SZ * U_SZ) / 64, 256, 0, stream>>>(part, out);
}